// Round 1
// 8658.795 us; speedup vs baseline: 1.4034x; 1.4034x over previous
//
#include <hip/hip_runtime.h>
#include <math.h>

// ---------------------------------------------------------------------------
// TensorProcessor: conv3d(1,3,1)+bias+relu -> Tucker-HOOI core (8,6,6,6)
// Round 7: latency-lean eigh. Thread remap (q=tid&3,row=tid>>2) puts the 4
// segment threads of a row in adjacent lanes -> cross-q combines are 2
// shfl_xor (no barrier/LDS). xnorm2/beta/tau computed redundantly per 4-lane
// group. w round-trip fused: publish w_pre + pu-partial, ONE barrier, then
// w_l reconstructed locally (exact symmetry kept via __fmul_rn/__fadd_rn).
// 2 barriers/Householder step (was 5). All divide chains (Sturm, invit,
// slarfg) use v_rcp_f32. MGS runs in a single wave with shuffle butterflies.
// conv/gram/contract/host code unchanged.
// ---------------------------------------------------------------------------

// ws layout (float offsets)
constexpr long long OFF_T   = 0LL;                 // 26,214,400
constexpr long long OFF_TC  = 26214400LL;          // 6,553,600
constexpr long long OFF_TB  = 32768000LL;          // 1,572,864
constexpr long long OFF_PART= OFF_TC;              // 240*16384 (init only)
constexpr long long OFF_TD0a= OFF_TC;              // mode0 (32,6,6,64)=73,728
constexpr long long OFF_TD0b= OFF_TC + 131072;     // mode0 (32,6,6,6)=6,912
constexpr long long OFF_TD  = OFF_TB + 1000000LL;  // sweep small tensors
constexpr long long OFF_G0  = OFF_TB + 1400000LL;  // 1,024
constexpr long long OFF_G1  = OFF_G0 + 1024;       // 10,000
constexpr long long OFF_G2  = OFF_G1 + 10000;      // 16,384
constexpr long long OFF_G3  = OFF_G2 + 16384;      // 4,096
constexpr long long OFF_F0  = 34340864LL;          // 256
constexpr long long OFF_F1  = OFF_F0 + 256;        // 600
constexpr long long OFF_F2  = OFF_F1 + 600;        // 768
constexpr long long OFF_F3  = OFF_F2 + 768;        // 384

__device__ __forceinline__ float rcp_(float x) { return __builtin_amdgcn_rcpf(x); }

// ---------------- conv + relu ----------------
__global__ void kconv(const float* __restrict__ x, const float* __restrict__ cw,
                      const float* __restrict__ cb, float* __restrict__ t) {
  int idx = blockIdx.x * blockDim.x + threadIdx.x;
  if (idx >= 26214400) return;
  int w  = idx & 63;
  int h  = (idx >> 6) & 127;
  int d  = (idx >> 13) % 100;
  int o  = idx / 819200;
  float acc = cb[o];
#pragma unroll
  for (int i = 0; i < 4; ++i) {
    const float* xi = x + (((long long)i * 100 + d) * 130 + h) * 64 + w;
#pragma unroll
    for (int kh = 0; kh < 3; ++kh)
      acc = fmaf(cw[(o * 4 + i) * 3 + kh], xi[kh * 64], acc);
  }
  t[idx] = fmaxf(acc, 0.f);
}

// ---------------- big gram (init HOSVD): G = X X^T over fibers ----------------
#define GRAM_BLOCKS 240
template<int D, long long QQ, bool TRANS>
__global__ void kgram_big(const float* __restrict__ T, float* __restrict__ part,
                          int P) {
  constexpr int C = 64;
  constexpr int SUB = (D + 63) / 64;
  constexpr int DP = SUB * 64;
  __shared__ float tile[DP * (C + 1)];
  const int tid = threadIdx.x;                 // 256
  const int ta = tid >> 4, tb = tid & 15;
  float acc[SUB][SUB][4][4];
#pragma unroll
  for (int a = 0; a < SUB; ++a)
#pragma unroll
    for (int b = 0; b < SUB; ++b)
#pragma unroll
      for (int i = 0; i < 4; ++i)
#pragma unroll
        for (int j = 0; j < 4; ++j) acc[a][b][i][j] = 0.f;

  const long long nfib = (long long)P * QQ;
  const int nchunk = (int)(nfib / C);
  for (int ch = blockIdx.x; ch < nchunk; ch += gridDim.x) {
    const long long base = (long long)ch * C;
    __syncthreads();
    if (TRANS) {
      for (int e = tid; e < D * C; e += 256) {
        int a = e & 63, cc = e >> 6;
        tile[a * (C + 1) + cc] = T[base * D + e];
      }
    } else {
      for (int e = tid; e < DP * C; e += 256) {
        int a = e / C, cc = e % C;
        float v = 0.f;
        if (a < D) {
          long long f = base + cc;
          long long p = f / QQ, q = f - p * QQ;   // compile-time QQ
          v = T[(p * D + a) * QQ + q];
        }
        tile[a * (C + 1) + cc] = v;
      }
    }
    __syncthreads();
    for (int cc = 0; cc < C; ++cc) {
      float av[SUB][4], bv[SUB][4];
#pragma unroll
      for (int si = 0; si < SUB; ++si)
#pragma unroll
        for (int i = 0; i < 4; ++i) av[si][i] = tile[(si * 64 + ta * 4 + i) * (C + 1) + cc];
#pragma unroll
      for (int sj = 0; sj < SUB; ++sj)
#pragma unroll
        for (int j = 0; j < 4; ++j) bv[sj][j] = tile[(sj * 64 + tb * 4 + j) * (C + 1) + cc];
#pragma unroll
      for (int si = 0; si < SUB; ++si)
#pragma unroll
        for (int sj = 0; sj < SUB; ++sj)
#pragma unroll
          for (int i = 0; i < 4; ++i)
#pragma unroll
            for (int j = 0; j < 4; ++j)
              acc[si][sj][i][j] = fmaf(av[si][i], bv[sj][j], acc[si][sj][i][j]);
    }
  }
  float* pb = part + (long long)blockIdx.x * D * D;
  for (int si = 0; si < SUB; ++si)
    for (int i = 0; i < 4; ++i) {
      int a = si * 64 + ta * 4 + i;
      if (a >= D) continue;
      for (int sj = 0; sj < SUB; ++sj)
        for (int j = 0; j < 4; ++j) {
          int b = sj * 64 + tb * 4 + j;
          if (b >= D) continue;
          pb[a * D + b] = acc[si][sj][i][j];
        }
    }
}

__global__ void kreduce(const float* __restrict__ part, float* __restrict__ G, int DD) {
  int i = blockIdx.x * blockDim.x + threadIdx.x;
  if (i >= DD) return;
  float s = 0.f;
  for (int b = 0; b < GRAM_BLOCKS; ++b) s += part[(long long)b * DD + i];
  G[i] = s;
}

// ---------------- small gram (projected Y) ----------------
__global__ void kgram_small(const float* __restrict__ Y, float* __restrict__ G,
                            int P, int d, int Q) {
  int pair = blockIdx.x * blockDim.x + threadIdx.x;
  if (pair >= d * d) return;
  int a = pair / d, b = pair % d;
  float s = 0.f;
  for (int p = 0; p < P; ++p) {
    const float* ya = Y + ((long long)p * d + a) * Q;
    const float* yb = Y + ((long long)p * d + b) * Q;
    for (int q = 0; q < Q; ++q) s = fmaf(ya[q], yb[q], s);
  }
  G[pair] = s;
}

// ---------------- mode contraction: out[p,j,q] = sum_a F[a,j] in[p,a,q] ----------------
template<int R, long long QV>
__global__ void kcontract(const float* __restrict__ in, const float* __restrict__ F,
                          float* __restrict__ out, int P, int d) {
  long long total = (long long)P * QV;
  long long idx = (long long)blockIdx.x * blockDim.x + threadIdx.x;
  if (idx >= total) return;
  long long p = idx / QV, q = idx - p * QV;
  float acc[R];
#pragma unroll
  for (int j = 0; j < R; ++j) acc[j] = 0.f;
  const float* ip = in + (p * d) * QV + q;
  for (int a = 0; a < d; ++a) {
    float v = ip[(long long)a * QV];
#pragma unroll
    for (int j = 0; j < R; ++j) acc[j] = fmaf(F[a * R + j], v, acc[j]);
  }
  float* op = out + (p * R) * QV + q;
#pragma unroll
  for (int j = 0; j < R; ++j) op[(long long)j * QV] = acc[j];
}

// ---------------- eigh: top-r eigenvectors of symmetric G (n<=128) ----------------
#define EIG_THREADS 512
#define EIG_WAVES 8

struct __align__(16) ESm {
  float ApkL[8256];              // packed-lower Householder columns (export)
  float colbuf[128];             // current pivot column (16B-aligned)
  float wwf[128];                // w_pre vector (pre-halfc)
  float dd[128], ee[128], e2s[128];
  float taus[128], scls[128];
  float vt[8][129];
  float slv[8][385];
  float lam[8];
  float red[EIG_WAVES];
  float sca[4];
};

template<int N, int RR>
__device__ void eig_body(ESm& S, const float* __restrict__ G, float* __restrict__ F) {
  constexpr int NP  = (N <= 32) ? 32 : ((N <= 64) ? 64 : 128);
  constexpr int QL  = NP / 4;          // floats per thread segment (8/16/32)
  constexpr int NC4 = QL / 4;          // float4 chunks per segment
  const int tid  = threadIdx.x;
  const int lane = tid & 63, wv = tid >> 6;
  const int q    = tid & 3;            // 4 adjacent lanes share a row
  const int row  = tid >> 2;           // 0..127
  const bool actR = (row < N);
  const int l0 = q * QL;

  float4* cb4 = (float4*)S.colbuf;
  float4* ww4 = (float4*)S.wwf;

  // ---- load: thread (row,q) owns A[row][l0 .. l0+QL) in VGPRs ----
  float Ar[QL];
#pragma unroll
  for (int j = 0; j < QL; ++j) Ar[j] = 0.f;
  if (actR) {
#pragma unroll
    for (int j = 0; j < QL; ++j) { int l = l0 + j; if (l < N) Ar[j] = G[row * N + l]; }
  }
  if (row == 0) {                      // colbuf <- column 0 = row 0 (pads exact 0)
#pragma unroll
    for (int c = 0; c < NC4; ++c)
      cb4[(l0 >> 2) + c] = make_float4(Ar[4*c], Ar[4*c+1], Ar[4*c+2], Ar[4*c+3]);
  }
  __syncthreads();

  // ---- Householder tridiagonalization (LAPACK slarfg conventions) ----
  // 2 barriers / step: (A) publish w_pre + pu partials, (B) publish pivot col.
  for (int i = 0; i <= N - 3; ++i) {
    // read column i: own segment + scalars (all pre-barrier-A, no WAR hazard)
    float cbs[QL];
#pragma unroll
    for (int c = 0; c < NC4; ++c) {
      float4 t = cb4[(l0 >> 2) + c];
      cbs[4*c] = t.x; cbs[4*c+1] = t.y; cbs[4*c+2] = t.z; cbs[4*c+3] = t.w;
    }
    float alpha = S.colbuf[i + 1];
    float myc   = (row < NP) ? S.colbuf[row] : 0.f;

    // xnorm2: segment partial, combined across q via 2 shfl_xor (no barrier).
    // Identical bitwise in every 4-lane group (same segments, same order).
    float prt = 0.f;
#pragma unroll
    for (int j = 0; j < QL; ++j) {
      int l = l0 + j;
      float v = (l >= i + 2) ? cbs[j] : 0.f;
      prt = fmaf(v, v, prt);
    }
    prt += __shfl_xor(prt, 1, 64);
    prt += __shfl_xor(prt, 2, 64);
    float xnorm2 = prt;
    float beta, tau_i, scl_i;
    if (xnorm2 == 0.f) { beta = alpha; tau_i = 0.f; scl_i = 0.f; }
    else {
      float an = sqrtf(alpha * alpha + xnorm2);
      beta = (alpha >= 0.f) ? -an : an;
      tau_i = (beta - alpha) * rcp_(beta);
      scl_i = rcp_(alpha - beta);
    }

    // u over own segment (registers, reused by symv and trailing update)
    float ul[QL];
#pragma unroll
    for (int j = 0; j < QL; ++j) {
      int l = l0 + j;
      ul[j] = (l == i + 1) ? 1.f : ((l >= i + 2) ? __fmul_rn(cbs[j], scl_i) : 0.f);
    }
    float u_row = 0.f;
    if (actR) {
      if (row == i + 1) u_row = 1.f;
      else if (row >= i + 2) u_row = __fmul_rn(myc, scl_i);
    }

    // symv partial from registers; cross-q via shfl_xor
    float s = 0.f;
#pragma unroll
    for (int j = 0; j < QL; ++j) s = fmaf(Ar[j], ul[j], s);
    s += __shfl_xor(s, 1, 64);
    s += __shfl_xor(s, 2, 64);                         // s_full for this row
    float w_pre = (actR && row >= i + 1) ? tau_i * s : 0.f;
    if (q == 0 && row < NP) S.wwf[row] = w_pre;
    // pu = sum_row w_pre*u_row : wave shfl reduce -> red[wv]
    float p2 = (q == 0) ? w_pre * u_row : 0.f;
#pragma unroll
    for (int off = 32; off > 0; off >>= 1) p2 += __shfl_down(p2, off, 64);
    if (lane == 0) S.red[wv] = p2;
    if (tid == 0) { S.ee[i] = beta; S.taus[i] = tau_i; S.scls[i] = scl_i; }
    __syncthreads();                                   // A: wwf + red visible

    float pu = 0.f;
#pragma unroll
    for (int w = 0; w < EIG_WAVES; ++w) pu += S.red[w];
    float halfc = -0.5f * tau_i * pu;
    float w_row = __fadd_rn(w_pre, __fmul_rn(halfc, u_row));
    // trailing update: w_l reconstructed locally; symmetric-exact (rn ops)
#pragma unroll
    for (int c = 0; c < NC4; ++c) {
      float4 t = ww4[(l0 >> 2) + c];
      float wlq[4] = {t.x, t.y, t.z, t.w};
#pragma unroll
      for (int jj = 0; jj < 4; ++jj) {
        int j = 4 * c + jj;
        float w_l = __fadd_rn(wlq[jj], __fmul_rn(halfc, ul[j]));
        Ar[j] -= __fadd_rn(__fmul_rn(u_row, w_l), __fmul_rn(w_row, ul[j]));
      }
    }
    if (row == i + 1) {                                // next pivot column = my row
#pragma unroll
      for (int c = 0; c < NC4; ++c)
        cb4[(l0 >> 2) + c] = make_float4(Ar[4*c], Ar[4*c+1], Ar[4*c+2], Ar[4*c+3]);
    }
    __syncthreads();                                   // B: colbuf visible
  }

  // ---- export diag + packed-lower Householder columns + last off-diag ----
  if (actR) {
    int base = (row * (row - 1)) >> 1;
#pragma unroll
    for (int j = 0; j < QL; ++j) {
      int l = l0 + j;
      if (l == row) S.dd[row] = Ar[j];
      if (l < row)  S.ApkL[base + l] = Ar[j];
      if (row == N - 1 && l == N - 2) S.ee[N - 2] = Ar[j];
    }
  }
  __syncthreads();
  if (tid < N) S.e2s[tid] = (tid >= 1) ? S.ee[tid - 1] * S.ee[tid - 1] : 0.f;

  // ---- Gershgorin bounds + pivmin ----
  if (tid == 0) {
    float lo = 3.4e38f, hi = -3.4e38f, me2 = 0.f;
    for (int ii = 0; ii < N; ++ii) {
      float rad = 0.f;
      if (ii > 0) rad += fabsf(S.ee[ii - 1]);
      if (ii < N - 1) { rad += fabsf(S.ee[ii]); me2 = fmaxf(me2, S.ee[ii] * S.ee[ii]); }
      lo = fminf(lo, S.dd[ii] - rad);
      hi = fmaxf(hi, S.dd[ii] + rad);
    }
    float span = hi - lo;
    S.sca[0] = lo - 0.001f * span - 1e-20f;
    S.sca[1] = hi + 0.001f * span + 1e-20f;
    S.sca[2] = 1.1754944e-38f * fmaxf(1.f, me2);
  }
  __syncthreads();
  const float pivmin = S.sca[2];

  // ---- 33-way multisection: 32 threads per eigenvalue, 8 rounds (rcp chain) ----
  {
    const int grp = tid >> 5, gt = tid & 31;
    if (grp < RR) {
      const int krank = N - 1 - grp;
      float lo = S.sca[0], hi = S.sca[1];
      for (int round = 0; round < 8; ++round) {
        float w = (hi - lo) * (1.f / 33.f);
        float sg = fmaf(w, (float)(gt + 1), lo);
        int cnt = 0;
        float qq = S.dd[0] - sg;
        if (qq < 0.f) cnt++;
        for (int ii = 1; ii < N; ++ii) {
          if (fabsf(qq) < pivmin) qq = -pivmin;
          qq = S.dd[ii] - sg - S.e2s[ii] * rcp_(qq);
          if (qq < 0.f) cnt++;
        }
        float nlo = (cnt <= krank) ? sg : lo;
        float nhi = (cnt >  krank) ? sg : hi;
#pragma unroll
        for (int off = 16; off > 0; off >>= 1) {
          nlo = fmaxf(nlo, __shfl_down(nlo, off, 32));
          nhi = fminf(nhi, __shfl_down(nhi, off, 32));
        }
        nlo = __shfl(nlo, 0, 32);
        nhi = __shfl(nhi, 0, 32);
        lo = fminf(nlo, nhi); hi = fmaxf(nlo, nhi);
      }
      if (gt == 0) S.lam[grp] = 0.5f * (lo + hi) * (1.f + (float)grp * 3e-7f);
    }
  }
  __syncthreads();

  // ---- inverse iteration, register-carried recurrence (rcp chain) ----
  if (tid < RR) {
    const int j = tid;
    float* u0 = &S.slv[j][0];
    float* u1 = &S.slv[j][128];
    float* u2 = &S.slv[j][256];
    float* vv = &S.vt[j][0];
    const float lj = S.lam[j];
    for (int k = 0; k < N; ++k) vv[k] = 1.f;
    for (int itr = 0; itr < 3; ++itr) {
      float d = S.dd[0] - lj;
      float e = S.ee[0];
      float cv = vv[0];
      for (int i = 0; i < N - 1; ++i) {
        float bi = S.ee[i];
        float d1 = S.dd[i + 1] - lj;
        float e1 = (i + 1 < N - 1) ? S.ee[i + 1] : 0.f;
        float vnext = vv[i + 1];
        float ai = d, ci = e;
        if (fabsf(ai) >= fabsf(bi)) {
          if (fabsf(ai) < pivmin) ai = (ai >= 0.f ? pivmin : -pivmin);
          float m = bi * rcp_(ai);
          u0[i] = ai; u1[i] = ci; u2[i] = 0.f;
          d = d1 - m * ci;
          e = e1;
          vv[i] = cv;
          cv = vnext - m * cv;
        } else {
          float m = ai * rcp_(bi);
          u0[i] = bi; u1[i] = d1; u2[i] = e1;
          d = ci - m * d1;
          e = -m * e1;
          vv[i] = vnext;
          cv = cv - m * vnext;
        }
      }
      if (fabsf(d) < pivmin) d = (d >= 0.f ? pivmin : -pivmin);
      float vi2 = cv * rcp_(d);
      vv[N - 1] = vi2;
      float vi1 = (vv[N - 2] - u1[N - 2] * vi2) * rcp_(u0[N - 2]);
      vv[N - 2] = vi1;
      for (int i = N - 3; i >= 0; --i) {
        float t = (vv[i] - u1[i] * vi1 - u2[i] * vi2) * rcp_(u0[i]);
        vv[i] = t;
        vi2 = vi1; vi1 = t;
      }
      float mx = 0.f;
      for (int k = 0; k < N; ++k) mx = fmaxf(mx, fabsf(vv[k]));
      float inv = rcp_(fmaxf(mx, 1e-30f));
      for (int k = 0; k < N; ++k) vv[k] *= inv;
    }
  }
  __syncthreads();

  // ---- MGS orthonormalization: single wave, shuffle butterflies ----
  if (wv == 0) {
    const int k1 = lane, k2 = lane + 64;
    for (int j = 0; j < RR; ++j) {
      float vj1 = (k1 < N) ? S.vt[j][k1] : 0.f;
      float vj2 = (k2 < N) ? S.vt[j][k2] : 0.f;
      for (int i2 = 0; i2 < j; ++i2) {
        float a1 = (k1 < N) ? S.vt[i2][k1] : 0.f;
        float a2 = (k2 < N) ? S.vt[i2][k2] : 0.f;
        float p = vj1 * a1 + vj2 * a2;
#pragma unroll
        for (int off = 32; off > 0; off >>= 1) p += __shfl_xor(p, off, 64);
        vj1 -= p * a1; vj2 -= p * a2;
      }
      float nn = vj1 * vj1 + vj2 * vj2;
#pragma unroll
      for (int off = 32; off > 0; off >>= 1) nn += __shfl_xor(nn, off, 64);
      float inv = rsqrtf(fmaxf(nn, 1e-33f));
      vj1 *= inv; vj2 *= inv;
      if (k1 < N) S.vt[j][k1] = vj1;
      if (k2 < N) S.vt[j][k2] = vj2;
    }
  }
  __syncthreads();

  // ---- back-transform: v = H_0 ... H_{N-3} v; uk cached in registers ----
  for (int vec = wv; vec < RR; vec += EIG_WAVES) {
    float* v = &S.vt[vec][0];
    const int k1 = lane, k2 = lane + 64;
    for (int h = N - 3; h >= 0; --h) {
      const float sh = S.scls[h];
      float uk1 = 0.f, uk2 = 0.f, dp = 0.f;
      if (k1 > h && k1 < N) {
        uk1 = (k1 == h + 1) ? 1.f : S.ApkL[((k1 * (k1 - 1)) >> 1) + h] * sh;
        dp += uk1 * v[k1];
      }
      if (k2 > h && k2 < N) {
        uk2 = (k2 == h + 1) ? 1.f : S.ApkL[((k2 * (k2 - 1)) >> 1) + h] * sh;
        dp += uk2 * v[k2];
      }
#pragma unroll
      for (int off = 32; off > 0; off >>= 1) dp += __shfl_xor(dp, off, 64);
      float c = S.taus[h] * dp;
      if (k1 > h && k1 < N) v[k1] -= c * uk1;
      if (k2 > h && k2 < N) v[k2] -= c * uk2;
    }
  }
  __syncthreads();

  // ---- canonical sign (max-|component| positive) + write F (N x RR) ----
  for (int vec = wv; vec < RR; vec += EIG_WAVES) {
    float* v = &S.vt[vec][0];
    float ma = -1.f; int mi = 0x7fffffff;
    for (int k = lane; k < N; k += 64) {
      float a = fabsf(v[k]);
      if (a > ma || (a == ma && k < mi)) { ma = a; mi = k; }
    }
#pragma unroll
    for (int off = 32; off > 0; off >>= 1) {
      float oa = __shfl_down(ma, off, 64);
      int oi = __shfl_down(mi, off, 64);
      if (oa > ma || (oa == ma && oi < mi)) { ma = oa; mi = oi; }
    }
    mi = __shfl(mi, 0, 64);
    float sg = (v[mi] < 0.f) ? -1.f : 1.f;
    for (int k = lane; k < N; k += 64) F[k * RR + vec] = sg * v[k];
  }
}

__global__ __launch_bounds__(EIG_THREADS, 1)
void keigh_init(const float* G0, float* F0, const float* G1, float* F1,
                const float* G2, float* F2, const float* G3, float* F3) {
  __shared__ ESm S;
  if (blockIdx.x == 0)      eig_body<32, 8>(S, G0, F0);
  else if (blockIdx.x == 1) eig_body<100, 6>(S, G1, F1);
  else if (blockIdx.x == 2) eig_body<128, 6>(S, G2, F2);
  else                      eig_body<64, 6>(S, G3, F3);
}

template<int N, int RR>
__global__ __launch_bounds__(EIG_THREADS, 1)
void keigh_one(const float* __restrict__ G, float* __restrict__ F) {
  __shared__ ESm S;
  eig_body<N, RR>(S, G, F);
}

// ---------------------------------------------------------------------------
extern "C" void kernel_launch(void* const* d_in, const int* in_sizes, int n_in,
                              void* d_out, int out_size, void* d_ws, size_t ws_size,
                              hipStream_t stream) {
  (void)in_sizes; (void)n_in; (void)out_size; (void)ws_size;
  const float* x  = (const float*)d_in[0];
  const float* cw = (const float*)d_in[1];
  const float* cb = (const float*)d_in[2];
  float* out = (float*)d_out;
  float* ws  = (float*)d_ws;

  float* T    = ws + OFF_T;
  float* TC   = ws + OFF_TC;
  float* TB   = ws + OFF_TB;
  float* PART = ws + OFF_PART;
  float* TD0a = ws + OFF_TD0a;
  float* TD0b = ws + OFF_TD0b;
  float* TD   = ws + OFF_TD;
  float* G0   = ws + OFF_G0;
  float* G1   = ws + OFF_G1;
  float* G2   = ws + OFF_G2;
  float* G3   = ws + OFF_G3;
  float* F0   = ws + OFF_F0;
  float* F1   = ws + OFF_F1;
  float* F2   = ws + OFF_F2;
  float* F3   = ws + OFF_F3;

  kconv<<<(26214400 + 255) / 256, 256, 0, stream>>>(x, cw, cb, T);

  // ---- HOSVD init: 4 grams, then one batched 4-block eigh ----
  kgram_big<32, 819200, false><<<GRAM_BLOCKS, 256, 0, stream>>>(T, PART, 1);
  kreduce<<<4, 256, 0, stream>>>(PART, G0, 1024);
  kgram_big<100, 8192, false><<<GRAM_BLOCKS, 256, 0, stream>>>(T, PART, 32);
  kreduce<<<40, 256, 0, stream>>>(PART, G1, 10000);
  kgram_big<128, 64, false><<<GRAM_BLOCKS, 256, 0, stream>>>(T, PART, 3200);
  kreduce<<<64, 256, 0, stream>>>(PART, G2, 16384);
  kgram_big<64, 1, true><<<GRAM_BLOCKS, 256, 0, stream>>>(T, PART, 409600);
  kreduce<<<16, 256, 0, stream>>>(PART, G3, 4096);

  keigh_init<<<4, EIG_THREADS, 0, stream>>>(G0, F0, G1, F1, G2, F2, G3, F3);

  // ---- HOOI sweeps ----
  for (int sweep = 0; sweep < 5; ++sweep) {
    // mode 0: Y = T x1 F1 x2 F2 x3 F3 -> (32,6,6,6)
    kcontract<6, 8192><<<1024, 256, 0, stream>>>(T, F1, TB, 32, 100);
    kcontract<6, 64><<<48, 256, 0, stream>>>(TB, F2, TD0a, 192, 128);
    kcontract<6, 1><<<5, 256, 0, stream>>>(TD0a, F3, TD0b, 1152, 64);
    kgram_small<<<4, 256, 0, stream>>>(TD0b, G0, 1, 32, 216);
    keigh_one<32, 8><<<1, EIG_THREADS, 0, stream>>>(G0, F0);
    // TC = T x0 F0 (reused by modes 1,2,3 and the final core)
    kcontract<8, 819200><<<3200, 256, 0, stream>>>(T, F0, TC, 1, 32);
    // mode 1
    kcontract<6, 64><<<200, 256, 0, stream>>>(TC, F2, TB, 800, 128);
    kcontract<6, 1><<<19, 256, 0, stream>>>(TB, F3, TD, 4800, 64);
    kgram_small<<<40, 256, 0, stream>>>(TD, G0, 8, 100, 36);
    keigh_one<100, 6><<<1, EIG_THREADS, 0, stream>>>(G0, F1);
    // mode 2 (TB = TC x1 F1 also reused by mode 3)
    kcontract<6, 8192><<<256, 256, 0, stream>>>(TC, F1, TB, 8, 100);
    kcontract<6, 1><<<24, 256, 0, stream>>>(TB, F3, TD, 6144, 64);
    kgram_small<<<64, 256, 0, stream>>>(TD, G0, 48, 128, 6);
    keigh_one<128, 6><<<1, EIG_THREADS, 0, stream>>>(G0, F2);
    // mode 3 (reuses TB from mode 2)
    kcontract<6, 64><<<12, 256, 0, stream>>>(TB, F2, TD, 48, 128);
    kgram_small<<<16, 256, 0, stream>>>(TD, G0, 288, 64, 1);
    keigh_one<64, 6><<<1, EIG_THREADS, 0, stream>>>(G0, F3);
  }

  // ---- core = (TC) x1 F1 x2 F2 x3 F3 -> (8,6,6,6) ----
  kcontract<6, 8192><<<256, 256, 0, stream>>>(TC, F1, TB, 8, 100);
  kcontract<6, 64><<<12, 256, 0, stream>>>(TB, F2, TD, 48, 128);
  kcontract<6, 1><<<2, 256, 0, stream>>>(TD, F3, out, 288, 64);
}

// Round 2
// 8554.462 us; speedup vs baseline: 1.4205x; 1.0122x over previous
//
#include <hip/hip_runtime.h>
#include <math.h>

// ---------------------------------------------------------------------------
// TensorProcessor: conv3d(1,3,1)+bias+relu -> Tucker-HOOI core (8,6,6,6)
// Round 8: DPP-based eigh. All intra-wave reductions use DPP (quad_perm /
// row_ror) at VALU latency instead of ds_swizzle shuffles (~100cy each).
// pu reduction: 2 DPP rors + 32 LDS partials read as float4 post-barrier.
// Wave gating: waves with no rows >= i+1 do bookkeeping-only + barriers.
// invit: float4-packed solver arrays (bank-padded), select-based pivoting,
// unroll-4 prefetch, scale-on-read normalization. Back-transform carries v
// in registers. Sturm: 6 rounds, DPP min/max. conv/gram/contract unchanged.
// ---------------------------------------------------------------------------

// ws layout (float offsets)
constexpr long long OFF_T   = 0LL;                 // 26,214,400
constexpr long long OFF_TC  = 26214400LL;          // 6,553,600
constexpr long long OFF_TB  = 32768000LL;          // 1,572,864
constexpr long long OFF_PART= OFF_TC;              // 240*16384 (init only)
constexpr long long OFF_TD0a= OFF_TC;              // mode0 (32,6,6,64)=73,728
constexpr long long OFF_TD0b= OFF_TC + 131072;     // mode0 (32,6,6,6)=6,912
constexpr long long OFF_TD  = OFF_TB + 1000000LL;  // sweep small tensors
constexpr long long OFF_G0  = OFF_TB + 1400000LL;  // 1,024
constexpr long long OFF_G1  = OFF_G0 + 1024;       // 10,000
constexpr long long OFF_G2  = OFF_G1 + 10000;      // 16,384
constexpr long long OFF_G3  = OFF_G2 + 16384;      // 4,096
constexpr long long OFF_F0  = 34340864LL;          // 256
constexpr long long OFF_F1  = OFF_F0 + 256;        // 600
constexpr long long OFF_F2  = OFF_F1 + 600;        // 768
constexpr long long OFF_F3  = OFF_F2 + 768;        // 384

__device__ __forceinline__ float rcp_(float x) { return __builtin_amdgcn_rcpf(x); }

template<int CTRL>
__device__ __forceinline__ float dppmovf(float v) {
  return __int_as_float(__builtin_amdgcn_update_dpp(
      0, __float_as_int(v), CTRL, 0xF, 0xF, true));
}
// sum over the 4-lane quad; bitwise-identical in all 4 lanes
__device__ __forceinline__ float quad_sum(float v) {
  v += dppmovf<0xB1>(v);    // quad_perm [1,0,3,2]  (xor 1)
  v += dppmovf<0x4E>(v);    // quad_perm [2,3,0,1]  (xor 2)
  return v;
}
// full 64-lane sum, result in all lanes (not bitwise lane-identical; ulp-level)
__device__ __forceinline__ float wave_sum64(float v) {
  v = quad_sum(v);
  v += dppmovf<0x124>(v);   // row_ror:4
  v += dppmovf<0x128>(v);   // row_ror:8  -> 16-row total in every lane
  v += __shfl_xor(v, 16, 64);
  v += __shfl_xor(v, 32, 64);
  return v;
}

// ---------------- conv + relu ----------------
__global__ void kconv(const float* __restrict__ x, const float* __restrict__ cw,
                      const float* __restrict__ cb, float* __restrict__ t) {
  int idx = blockIdx.x * blockDim.x + threadIdx.x;
  if (idx >= 26214400) return;
  int w  = idx & 63;
  int h  = (idx >> 6) & 127;
  int d  = (idx >> 13) % 100;
  int o  = idx / 819200;
  float acc = cb[o];
#pragma unroll
  for (int i = 0; i < 4; ++i) {
    const float* xi = x + (((long long)i * 100 + d) * 130 + h) * 64 + w;
#pragma unroll
    for (int kh = 0; kh < 3; ++kh)
      acc = fmaf(cw[(o * 4 + i) * 3 + kh], xi[kh * 64], acc);
  }
  t[idx] = fmaxf(acc, 0.f);
}

// ---------------- big gram (init HOSVD): G = X X^T over fibers ----------------
#define GRAM_BLOCKS 240
template<int D, long long QQ, bool TRANS>
__global__ void kgram_big(const float* __restrict__ T, float* __restrict__ part,
                          int P) {
  constexpr int C = 64;
  constexpr int SUB = (D + 63) / 64;
  constexpr int DP = SUB * 64;
  __shared__ float tile[DP * (C + 1)];
  const int tid = threadIdx.x;                 // 256
  const int ta = tid >> 4, tb = tid & 15;
  float acc[SUB][SUB][4][4];
#pragma unroll
  for (int a = 0; a < SUB; ++a)
#pragma unroll
    for (int b = 0; b < SUB; ++b)
#pragma unroll
      for (int i = 0; i < 4; ++i)
#pragma unroll
        for (int j = 0; j < 4; ++j) acc[a][b][i][j] = 0.f;

  const long long nfib = (long long)P * QQ;
  const int nchunk = (int)(nfib / C);
  for (int ch = blockIdx.x; ch < nchunk; ch += gridDim.x) {
    const long long base = (long long)ch * C;
    __syncthreads();
    if (TRANS) {
      for (int e = tid; e < D * C; e += 256) {
        int a = e & 63, cc = e >> 6;
        tile[a * (C + 1) + cc] = T[base * D + e];
      }
    } else {
      for (int e = tid; e < DP * C; e += 256) {
        int a = e / C, cc = e % C;
        float v = 0.f;
        if (a < D) {
          long long f = base + cc;
          long long p = f / QQ, q = f - p * QQ;   // compile-time QQ
          v = T[(p * D + a) * QQ + q];
        }
        tile[a * (C + 1) + cc] = v;
      }
    }
    __syncthreads();
    for (int cc = 0; cc < C; ++cc) {
      float av[SUB][4], bv[SUB][4];
#pragma unroll
      for (int si = 0; si < SUB; ++si)
#pragma unroll
        for (int i = 0; i < 4; ++i) av[si][i] = tile[(si * 64 + ta * 4 + i) * (C + 1) + cc];
#pragma unroll
      for (int sj = 0; sj < SUB; ++sj)
#pragma unroll
        for (int j = 0; j < 4; ++j) bv[sj][j] = tile[(sj * 64 + tb * 4 + j) * (C + 1) + cc];
#pragma unroll
      for (int si = 0; si < SUB; ++si)
#pragma unroll
        for (int sj = 0; sj < SUB; ++sj)
#pragma unroll
          for (int i = 0; i < 4; ++i)
#pragma unroll
            for (int j = 0; j < 4; ++j)
              acc[si][sj][i][j] = fmaf(av[si][i], bv[sj][j], acc[si][sj][i][j]);
    }
  }
  float* pb = part + (long long)blockIdx.x * D * D;
  for (int si = 0; si < SUB; ++si)
    for (int i = 0; i < 4; ++i) {
      int a = si * 64 + ta * 4 + i;
      if (a >= D) continue;
      for (int sj = 0; sj < SUB; ++sj)
        for (int j = 0; j < 4; ++j) {
          int b = sj * 64 + tb * 4 + j;
          if (b >= D) continue;
          pb[a * D + b] = acc[si][sj][i][j];
        }
    }
}

__global__ void kreduce(const float* __restrict__ part, float* __restrict__ G, int DD) {
  int i = blockIdx.x * blockDim.x + threadIdx.x;
  if (i >= DD) return;
  float s = 0.f;
  for (int b = 0; b < GRAM_BLOCKS; ++b) s += part[(long long)b * DD + i];
  G[i] = s;
}

// ---------------- small gram (projected Y) ----------------
__global__ void kgram_small(const float* __restrict__ Y, float* __restrict__ G,
                            int P, int d, int Q) {
  int pair = blockIdx.x * blockDim.x + threadIdx.x;
  if (pair >= d * d) return;
  int a = pair / d, b = pair % d;
  float s = 0.f;
  for (int p = 0; p < P; ++p) {
    const float* ya = Y + ((long long)p * d + a) * Q;
    const float* yb = Y + ((long long)p * d + b) * Q;
    for (int q = 0; q < Q; ++q) s = fmaf(ya[q], yb[q], s);
  }
  G[pair] = s;
}

// ---------------- mode contraction: out[p,j,q] = sum_a F[a,j] in[p,a,q] ----------------
template<int R, long long QV>
__global__ void kcontract(const float* __restrict__ in, const float* __restrict__ F,
                          float* __restrict__ out, int P, int d) {
  long long total = (long long)P * QV;
  long long idx = (long long)blockIdx.x * blockDim.x + threadIdx.x;
  if (idx >= total) return;
  long long p = idx / QV, q = idx - p * QV;
  float acc[R];
#pragma unroll
  for (int j = 0; j < R; ++j) acc[j] = 0.f;
  const float* ip = in + (p * d) * QV + q;
  for (int a = 0; a < d; ++a) {
    float v = ip[(long long)a * QV];
#pragma unroll
    for (int j = 0; j < R; ++j) acc[j] = fmaf(F[a * R + j], v, acc[j]);
  }
  float* op = out + (p * R) * QV + q;
#pragma unroll
  for (int j = 0; j < R; ++j) op[(long long)j * QV] = acc[j];
}

// ---------------- eigh: top-r eigenvectors of symmetric G (n<=128) ----------------
#define EIG_THREADS 512
#define EIG_WAVES 8

struct __align__(16) ESm {
  float ApkL[8256];              // packed-lower Householder columns (export)
  float colbuf[128];             // current pivot column (16B-aligned)
  float wwf[128];                // w_pre vector
  float slv[8][516];             // invit solver: float4 {u0,u1,u2,-} per i, bank-padded
  float dd[128], ee[128], e2s[128], taus[128], scls[128];
  float vt[8][132];
  float lam[8];
  float red[32];                 // per-16-row pu partials
  float sca[4];
};

template<int N, int RR>
__device__ void eig_body(ESm& S, const float* __restrict__ G, float* __restrict__ F) {
  constexpr int NP  = (N <= 32) ? 32 : ((N <= 64) ? 64 : 128);
  constexpr int QL  = NP / 4;          // floats per thread segment (8/16/32)
  constexpr int NC4 = QL / 4;          // float4 chunks per segment
  const int tid  = threadIdx.x;
  const int lane = tid & 63, wv = tid >> 6;
  const int q    = tid & 3;            // 4 adjacent lanes share a row
  const int row  = tid >> 2;           // 0..127
  const bool actR = (row < N);
  const int l0 = q * QL;

  float4* cb4 = (float4*)S.colbuf;
  float4* ww4 = (float4*)S.wwf;

  // ---- load: thread (row,q) owns A[row][l0 .. l0+QL) in VGPRs ----
  float Ar[QL];
#pragma unroll
  for (int j = 0; j < QL; ++j) Ar[j] = 0.f;
  if (actR) {
#pragma unroll
    for (int j = 0; j < QL; ++j) { int l = l0 + j; if (l < N) Ar[j] = G[row * N + l]; }
  }
  if (row == 0) {                      // colbuf <- column 0 = row 0 (pads exact 0)
#pragma unroll
    for (int c = 0; c < NC4; ++c)
      cb4[(l0 >> 2) + c] = make_float4(Ar[4*c], Ar[4*c+1], Ar[4*c+2], Ar[4*c+3]);
  }
  __syncthreads();

  // ---- Householder tridiagonalization (LAPACK slarfg conventions) ----
  const int wrow0 = wv << 4;           // 16 rows per wave
  for (int i = 0; i <= N - 3; ++i) {
    const bool wact = (wrow0 + 15 >= i + 1) && (wrow0 <= N - 1);
    float tau_i = 0.f, u_row = 0.f, w_pre = 0.f;
    float ul[NC4 * 4];
    bool cg[NC4];
    if (wact) {
      float cbs[QL];
#pragma unroll
      for (int c = 0; c < NC4; ++c) {
        float4 t = cb4[(l0 >> 2) + c];
        cbs[4*c] = t.x; cbs[4*c+1] = t.y; cbs[4*c+2] = t.z; cbs[4*c+3] = t.w;
        cg[c] = (l0 + 4*c + 3 >= i + 1);
      }
      float alpha = S.colbuf[i + 1];
      float myc   = S.colbuf[row];

      // xnorm2 via 4 accumulators + quad DPP (bitwise-identical per quad)
      float nn[4] = {0.f, 0.f, 0.f, 0.f};
#pragma unroll
      for (int c = 0; c < NC4; ++c) if (cg[c]) {
#pragma unroll
        for (int jj = 0; jj < 4; ++jj) {
          int l = l0 + 4*c + jj;
          float v = (l >= i + 2) ? cbs[4*c+jj] : 0.f;
          nn[jj] = fmaf(v, v, nn[jj]);
        }
      }
      float xnorm2 = quad_sum((nn[0] + nn[1]) + (nn[2] + nn[3]));
      float beta, scl_i;
      if (xnorm2 == 0.f) { beta = alpha; tau_i = 0.f; scl_i = 0.f; }
      else {
        float an = sqrtf(alpha * alpha + xnorm2);
        beta = (alpha >= 0.f) ? -an : an;
        tau_i = (beta - alpha) * rcp_(beta);
        scl_i = rcp_(alpha - beta);
      }
#pragma unroll
      for (int c = 0; c < NC4; ++c)
#pragma unroll
        for (int jj = 0; jj < 4; ++jj) {
          int j = 4*c + jj, l = l0 + j;
          ul[j] = (l == i + 1) ? 1.f : ((l >= i + 2) ? __fmul_rn(cbs[j], scl_i) : 0.f);
        }
      if (actR) {
        if (row == i + 1) u_row = 1.f;
        else if (row >= i + 2) u_row = __fmul_rn(myc, scl_i);
      }
      // symv: 4 accumulators + quad DPP
      float sa[4] = {0.f, 0.f, 0.f, 0.f};
#pragma unroll
      for (int c = 0; c < NC4; ++c) if (cg[c]) {
#pragma unroll
        for (int jj = 0; jj < 4; ++jj)
          sa[jj] = fmaf(Ar[4*c+jj], ul[4*c+jj], sa[jj]);
      }
      float s = quad_sum((sa[0] + sa[1]) + (sa[2] + sa[3]));
      w_pre = (actR && row >= i + 1) ? tau_i * s : 0.f;
      if (q == 0) S.wwf[row] = w_pre;
      // pu partials: quad-identical -> row_ror sums over the 4 rows of each 16-group
      float p2 = w_pre * u_row;
      p2 += dppmovf<0x124>(p2);
      p2 += dppmovf<0x128>(p2);
      if ((lane & 15) == 0) S.red[(wv << 2) + (lane >> 4)] = p2;
      if (row == i + 1 && q == 0) { S.ee[i] = beta; S.taus[i] = tau_i; S.scls[i] = scl_i; }
    } else {
      if (q == 0) S.wwf[row] = 0.f;
      if ((lane & 15) == 0) S.red[(wv << 2) + (lane >> 4)] = 0.f;
    }
    __syncthreads();                                   // A: wwf + red visible
    if (wact) {
      float4* r4 = (float4*)S.red;
      float pu = 0.f;
#pragma unroll
      for (int c = 0; c < 8; ++c) { float4 t = r4[c]; pu += ((t.x + t.y) + (t.z + t.w)); }
      float halfc = -0.5f * tau_i * pu;
      float w_row = __fadd_rn(w_pre, __fmul_rn(halfc, u_row));
#pragma unroll
      for (int c = 0; c < NC4; ++c) if (cg[c]) {
        float4 t = ww4[(l0 >> 2) + c];
        float wlq[4] = {t.x, t.y, t.z, t.w};
#pragma unroll
        for (int jj = 0; jj < 4; ++jj) {
          int j = 4*c + jj;
          float w_l = __fadd_rn(wlq[jj], __fmul_rn(halfc, ul[j]));
          Ar[j] -= __fadd_rn(__fmul_rn(u_row, w_l), __fmul_rn(w_row, ul[j]));
        }
      }
      if (row == i + 1) {                              // next pivot column = my row
#pragma unroll
        for (int c = 0; c < NC4; ++c)
          cb4[(l0 >> 2) + c] = make_float4(Ar[4*c], Ar[4*c+1], Ar[4*c+2], Ar[4*c+3]);
      }
    }
    __syncthreads();                                   // B: colbuf visible
  }

  // ---- export diag + packed-lower Householder columns + last off-diag ----
  if (actR) {
    int base = (row * (row - 1)) >> 1;
#pragma unroll
    for (int j = 0; j < QL; ++j) {
      int l = l0 + j;
      if (l == row) S.dd[row] = Ar[j];
      if (l < row)  S.ApkL[base + l] = Ar[j];
      if (row == N - 1 && l == N - 2) S.ee[N - 2] = Ar[j];
    }
  }
  __syncthreads();
  if (tid < N) S.e2s[tid] = (tid >= 1) ? S.ee[tid - 1] * S.ee[tid - 1] : 0.f;

  // ---- Gershgorin bounds + pivmin ----
  if (tid == 0) {
    float lo = 3.4e38f, hi = -3.4e38f, me2 = 0.f;
    for (int ii = 0; ii < N; ++ii) {
      float rad = 0.f;
      if (ii > 0) rad += fabsf(S.ee[ii - 1]);
      if (ii < N - 1) { rad += fabsf(S.ee[ii]); me2 = fmaxf(me2, S.ee[ii] * S.ee[ii]); }
      lo = fminf(lo, S.dd[ii] - rad);
      hi = fmaxf(hi, S.dd[ii] + rad);
    }
    float span = hi - lo;
    S.sca[0] = lo - 0.001f * span - 1e-20f;
    S.sca[1] = hi + 0.001f * span + 1e-20f;
    S.sca[2] = 1.1754944e-38f * fmaxf(1.f, me2);
  }
  __syncthreads();
  const float pivmin = S.sca[2];

  // ---- 33-way multisection: 32 threads per eigenvalue, 6 rounds ----
  {
    const int grp = tid >> 5, gt = tid & 31;
    if (grp < RR) {
      const int krank = N - 1 - grp;
      float lo = S.sca[0], hi = S.sca[1];
      for (int round = 0; round < 6; ++round) {
        float w = (hi - lo) * (1.f / 33.f);
        float sg = fmaf(w, (float)(gt + 1), lo);
        int cnt = 0;
        float qq = S.dd[0] - sg;
        if (qq < 0.f) cnt++;
#pragma unroll 4
        for (int ii = 1; ii < N; ++ii) {
          if (fabsf(qq) < pivmin) qq = -pivmin;
          qq = S.dd[ii] - sg - S.e2s[ii] * rcp_(qq);
          if (qq < 0.f) cnt++;
        }
        float nlo = (cnt <= krank) ? sg : lo;
        float nhi = (cnt >  krank) ? sg : hi;
        nlo = fmaxf(nlo, dppmovf<0xB1>(nlo));  nhi = fminf(nhi, dppmovf<0xB1>(nhi));
        nlo = fmaxf(nlo, dppmovf<0x4E>(nlo));  nhi = fminf(nhi, dppmovf<0x4E>(nhi));
        nlo = fmaxf(nlo, dppmovf<0x124>(nlo)); nhi = fminf(nhi, dppmovf<0x124>(nhi));
        nlo = fmaxf(nlo, dppmovf<0x128>(nlo)); nhi = fminf(nhi, dppmovf<0x128>(nhi));
        nlo = fmaxf(nlo, __shfl_xor(nlo, 16, 32));
        nhi = fminf(nhi, __shfl_xor(nhi, 16, 32));
        lo = fminf(nlo, nhi); hi = fmaxf(nlo, nhi);
      }
      if (gt == 0) S.lam[grp] = 0.5f * (lo + hi) * (1.f + (float)grp * 3e-7f);
    }
  }
  __syncthreads();

  // ---- inverse iteration: float4-packed solver, select pivoting, prefetch ----
  if (tid < RR) {
    const int j = tid;
    float4* u4 = (float4*)&S.slv[j][0];
    float* vv = &S.vt[j][0];
    const float lj = S.lam[j];
    for (int k = 0; k < N; ++k) vv[k] = 1.f;
    float sc = 1.f;
    for (int itr = 0; itr < 3; ++itr) {
      float d = S.dd[0] - lj;
      float e = S.ee[0];
      float cv = vv[0] * sc;
#pragma unroll 4
      for (int i = 0; i < N - 1; ++i) {
        float bi = S.ee[i];
        float d1 = S.dd[i + 1] - lj;
        float e1 = (i + 1 < N - 1) ? S.ee[i + 1] : 0.f;
        float vnext = vv[i + 1] * sc;
        bool piv = (fabsf(d) >= fabsf(bi));
        float ad = d;
        if (piv && fabsf(ad) < pivmin) ad = (ad >= 0.f ? pivmin : -pivmin);
        float m   = piv ? (bi * rcp_(ad)) : (ad * rcp_(bi));
        float nu0 = piv ? ad : bi;
        float nu1 = piv ? e  : d1;
        float nu2 = piv ? 0.f : e1;
        u4[i] = make_float4(nu0, nu1, nu2, 0.f);
        float nd = piv ? (d1 - m * e) : (e - m * d1);
        float ne = piv ? e1 : (-m * e1);
        vv[i] = piv ? cv : vnext;
        cv = piv ? (vnext - m * cv) : (cv - m * vnext);
        d = nd; e = ne;
      }
      if (fabsf(d) < pivmin) d = (d >= 0.f ? pivmin : -pivmin);
      float vi2 = cv * rcp_(d);
      vv[N - 1] = vi2;
      float mx = fabsf(vi2);
      float4 uN2 = u4[N - 2];
      float vi1 = (vv[N - 2] - uN2.y * vi2) * rcp_(uN2.x);
      vv[N - 2] = vi1;
      mx = fmaxf(mx, fabsf(vi1));
#pragma unroll 4
      for (int i = N - 3; i >= 0; --i) {
        float4 u = u4[i];
        float t = (vv[i] - u.y * vi1 - u.z * vi2) * rcp_(u.x);
        vv[i] = t;
        mx = fmaxf(mx, fabsf(t));
        vi2 = vi1; vi1 = t;
      }
      sc = rcp_(fmaxf(mx, 1e-30f));
    }
    for (int k = 0; k < N; ++k) vv[k] *= sc;   // final normalize (overflow guard)
  }
  __syncthreads();

  // ---- MGS orthonormalization: single wave, DPP reductions ----
  if (wv == 0) {
    const int k1 = lane, k2 = lane + 64;
    for (int j = 0; j < RR; ++j) {
      float vj1 = (k1 < N) ? S.vt[j][k1] : 0.f;
      float vj2 = (k2 < N) ? S.vt[j][k2] : 0.f;
      for (int i2 = 0; i2 < j; ++i2) {
        float a1 = (k1 < N) ? S.vt[i2][k1] : 0.f;
        float a2 = (k2 < N) ? S.vt[i2][k2] : 0.f;
        float p = wave_sum64(vj1 * a1 + vj2 * a2);
        vj1 -= p * a1; vj2 -= p * a2;
      }
      float nn2 = wave_sum64(vj1 * vj1 + vj2 * vj2);
      float inv = rsqrtf(fmaxf(nn2, 1e-33f));
      vj1 *= inv; vj2 *= inv;
      if (k1 < N) S.vt[j][k1] = vj1;
      if (k2 < N) S.vt[j][k2] = vj2;
    }
  }
  __syncthreads();

  // ---- back-transform: v carried in registers; DPP reductions ----
  for (int vec = wv; vec < RR; vec += EIG_WAVES) {
    float* v = &S.vt[vec][0];
    const int k1 = lane, k2 = lane + 64;
    float v1 = (k1 < N) ? v[k1] : 0.f;
    float v2 = (k2 < N) ? v[k2] : 0.f;
    for (int h = N - 3; h >= 0; --h) {
      const float sh = S.scls[h];
      float uk1 = 0.f, uk2 = 0.f;
      if (k1 > h && k1 < N)
        uk1 = (k1 == h + 1) ? 1.f : S.ApkL[((k1 * (k1 - 1)) >> 1) + h] * sh;
      if (k2 > h && k2 < N)
        uk2 = (k2 == h + 1) ? 1.f : S.ApkL[((k2 * (k2 - 1)) >> 1) + h] * sh;
      float dp = wave_sum64(uk1 * v1 + uk2 * v2);
      float c = S.taus[h] * dp;
      v1 -= c * uk1; v2 -= c * uk2;
    }
    if (k1 < N) v[k1] = v1;
    if (k2 < N) v[k2] = v2;
  }
  __syncthreads();

  // ---- canonical sign (max-|component| positive) + write F (N x RR) ----
  for (int vec = wv; vec < RR; vec += EIG_WAVES) {
    float* v = &S.vt[vec][0];
    float ma = -1.f; int mi = 0x7fffffff;
    for (int k = lane; k < N; k += 64) {
      float a = fabsf(v[k]);
      if (a > ma || (a == ma && k < mi)) { ma = a; mi = k; }
    }
#pragma unroll
    for (int off = 32; off > 0; off >>= 1) {
      float oa = __shfl_down(ma, off, 64);
      int oi = __shfl_down(mi, off, 64);
      if (oa > ma || (oa == ma && oi < mi)) { ma = oa; mi = oi; }
    }
    mi = __shfl(mi, 0, 64);
    float sg = (v[mi] < 0.f) ? -1.f : 1.f;
    for (int k = lane; k < N; k += 64) F[k * RR + vec] = sg * v[k];
  }
}

__global__ __launch_bounds__(EIG_THREADS, 1)
void keigh_init(const float* G0, float* F0, const float* G1, float* F1,
                const float* G2, float* F2, const float* G3, float* F3) {
  __shared__ ESm S;
  if (blockIdx.x == 0)      eig_body<32, 8>(S, G0, F0);
  else if (blockIdx.x == 1) eig_body<100, 6>(S, G1, F1);
  else if (blockIdx.x == 2) eig_body<128, 6>(S, G2, F2);
  else                      eig_body<64, 6>(S, G3, F3);
}

template<int N, int RR>
__global__ __launch_bounds__(EIG_THREADS, 1)
void keigh_one(const float* __restrict__ G, float* __restrict__ F) {
  __shared__ ESm S;
  eig_body<N, RR>(S, G, F);
}

// ---------------------------------------------------------------------------
extern "C" void kernel_launch(void* const* d_in, const int* in_sizes, int n_in,
                              void* d_out, int out_size, void* d_ws, size_t ws_size,
                              hipStream_t stream) {
  (void)in_sizes; (void)n_in; (void)out_size; (void)ws_size;
  const float* x  = (const float*)d_in[0];
  const float* cw = (const float*)d_in[1];
  const float* cb = (const float*)d_in[2];
  float* out = (float*)d_out;
  float* ws  = (float*)d_ws;

  float* T    = ws + OFF_T;
  float* TC   = ws + OFF_TC;
  float* TB   = ws + OFF_TB;
  float* PART = ws + OFF_PART;
  float* TD0a = ws + OFF_TD0a;
  float* TD0b = ws + OFF_TD0b;
  float* TD   = ws + OFF_TD;
  float* G0   = ws + OFF_G0;
  float* G1   = ws + OFF_G1;
  float* G2   = ws + OFF_G2;
  float* G3   = ws + OFF_G3;
  float* F0   = ws + OFF_F0;
  float* F1   = ws + OFF_F1;
  float* F2   = ws + OFF_F2;
  float* F3   = ws + OFF_F3;

  kconv<<<(26214400 + 255) / 256, 256, 0, stream>>>(x, cw, cb, T);

  // ---- HOSVD init: 4 grams, then one batched 4-block eigh ----
  kgram_big<32, 819200, false><<<GRAM_BLOCKS, 256, 0, stream>>>(T, PART, 1);
  kreduce<<<4, 256, 0, stream>>>(PART, G0, 1024);
  kgram_big<100, 8192, false><<<GRAM_BLOCKS, 256, 0, stream>>>(T, PART, 32);
  kreduce<<<40, 256, 0, stream>>>(PART, G1, 10000);
  kgram_big<128, 64, false><<<GRAM_BLOCKS, 256, 0, stream>>>(T, PART, 3200);
  kreduce<<<64, 256, 0, stream>>>(PART, G2, 16384);
  kgram_big<64, 1, true><<<GRAM_BLOCKS, 256, 0, stream>>>(T, PART, 409600);
  kreduce<<<16, 256, 0, stream>>>(PART, G3, 4096);

  keigh_init<<<4, EIG_THREADS, 0, stream>>>(G0, F0, G1, F1, G2, F2, G3, F3);

  // ---- HOOI sweeps ----
  for (int sweep = 0; sweep < 5; ++sweep) {
    // mode 0: Y = T x1 F1 x2 F2 x3 F3 -> (32,6,6,6)
    kcontract<6, 8192><<<1024, 256, 0, stream>>>(T, F1, TB, 32, 100);
    kcontract<6, 64><<<48, 256, 0, stream>>>(TB, F2, TD0a, 192, 128);
    kcontract<6, 1><<<5, 256, 0, stream>>>(TD0a, F3, TD0b, 1152, 64);
    kgram_small<<<4, 256, 0, stream>>>(TD0b, G0, 1, 32, 216);
    keigh_one<32, 8><<<1, EIG_THREADS, 0, stream>>>(G0, F0);
    // TC = T x0 F0 (reused by modes 1,2,3 and the final core)
    kcontract<8, 819200><<<3200, 256, 0, stream>>>(T, F0, TC, 1, 32);
    // mode 1
    kcontract<6, 64><<<200, 256, 0, stream>>>(TC, F2, TB, 800, 128);
    kcontract<6, 1><<<19, 256, 0, stream>>>(TB, F3, TD, 4800, 64);
    kgram_small<<<40, 256, 0, stream>>>(TD, G0, 8, 100, 36);
    keigh_one<100, 6><<<1, EIG_THREADS, 0, stream>>>(G0, F1);
    // mode 2 (TB = TC x1 F1 also reused by mode 3)
    kcontract<6, 8192><<<256, 256, 0, stream>>>(TC, F1, TB, 8, 100);
    kcontract<6, 1><<<24, 256, 0, stream>>>(TB, F3, TD, 6144, 64);
    kgram_small<<<64, 256, 0, stream>>>(TD, G0, 48, 128, 6);
    keigh_one<128, 6><<<1, EIG_THREADS, 0, stream>>>(G0, F2);
    // mode 3 (reuses TB from mode 2)
    kcontract<6, 64><<<12, 256, 0, stream>>>(TB, F2, TD, 48, 128);
    kgram_small<<<16, 256, 0, stream>>>(TD, G0, 288, 64, 1);
    keigh_one<64, 6><<<1, EIG_THREADS, 0, stream>>>(G0, F3);
  }

  // ---- core = (TC) x1 F1 x2 F2 x3 F3 -> (8,6,6,6) ----
  kcontract<6, 8192><<<256, 256, 0, stream>>>(TC, F1, TB, 8, 100);
  kcontract<6, 64><<<12, 256, 0, stream>>>(TB, F2, TD, 48, 128);
  kcontract<6, 1><<<2, 256, 0, stream>>>(TD, F3, out, 288, 64);
}

// Round 3
// 7254.077 us; speedup vs baseline: 1.6751x; 1.1793x over previous
//
#include <hip/hip_runtime.h>
#include <math.h>

// ---------------------------------------------------------------------------
// TensorProcessor: conv3d(1,3,1)+bias+relu -> Tucker-HOOI core (8,6,6,6)
// Round 9: 8-lane row split eigh. 1024 threads (16 waves, 4/SIMD) so each
// thread owns QL=NP/8 elements -> per-wave issue halves and 4 waves/SIMD
// hide latency (round-8 showed latency-bound at 2 waves/SIMD). Cross-segment
// combines: 2 DPP + shfl_xor(4). Trailing update now 3 fma/element (dropped
// exact-symmetry rounding; ~1ulp/step asymmetry, absorbed by MGS + tolerance).
// Wave gating at 8-row granularity. conv/gram/contract/host unchanged.
// ---------------------------------------------------------------------------

// ws layout (float offsets)
constexpr long long OFF_T   = 0LL;                 // 26,214,400
constexpr long long OFF_TC  = 26214400LL;          // 6,553,600
constexpr long long OFF_TB  = 32768000LL;          // 1,572,864
constexpr long long OFF_PART= OFF_TC;              // 240*16384 (init only)
constexpr long long OFF_TD0a= OFF_TC;              // mode0 (32,6,6,64)=73,728
constexpr long long OFF_TD0b= OFF_TC + 131072;     // mode0 (32,6,6,6)=6,912
constexpr long long OFF_TD  = OFF_TB + 1000000LL;  // sweep small tensors
constexpr long long OFF_G0  = OFF_TB + 1400000LL;  // 1,024
constexpr long long OFF_G1  = OFF_G0 + 1024;       // 10,000
constexpr long long OFF_G2  = OFF_G1 + 10000;      // 16,384
constexpr long long OFF_G3  = OFF_G2 + 16384;      // 4,096
constexpr long long OFF_F0  = 34340864LL;          // 256
constexpr long long OFF_F1  = OFF_F0 + 256;        // 600
constexpr long long OFF_F2  = OFF_F1 + 600;        // 768
constexpr long long OFF_F3  = OFF_F2 + 768;        // 384

__device__ __forceinline__ float rcp_(float x) { return __builtin_amdgcn_rcpf(x); }

template<int CTRL>
__device__ __forceinline__ float dppmovf(float v) {
  return __int_as_float(__builtin_amdgcn_update_dpp(
      0, __float_as_int(v), CTRL, 0xF, 0xF, true));
}
// sum over 8 consecutive lanes (lane-symmetric, identical in all 8)
__device__ __forceinline__ float oct_sum(float v) {
  v += dppmovf<0xB1>(v);    // quad_perm xor1
  v += dppmovf<0x4E>(v);    // quad_perm xor2
  v += __shfl_xor(v, 4, 64);
  return v;
}
// full 64-lane sum, result in all lanes
__device__ __forceinline__ float wave_sum64(float v) {
  v += dppmovf<0xB1>(v);
  v += dppmovf<0x4E>(v);
  v += dppmovf<0x124>(v);   // row_ror:4
  v += dppmovf<0x128>(v);   // row_ror:8
  v += __shfl_xor(v, 16, 64);
  v += __shfl_xor(v, 32, 64);
  return v;
}

// ---------------- conv + relu ----------------
__global__ void kconv(const float* __restrict__ x, const float* __restrict__ cw,
                      const float* __restrict__ cb, float* __restrict__ t) {
  int idx = blockIdx.x * blockDim.x + threadIdx.x;
  if (idx >= 26214400) return;
  int w  = idx & 63;
  int h  = (idx >> 6) & 127;
  int d  = (idx >> 13) % 100;
  int o  = idx / 819200;
  float acc = cb[o];
#pragma unroll
  for (int i = 0; i < 4; ++i) {
    const float* xi = x + (((long long)i * 100 + d) * 130 + h) * 64 + w;
#pragma unroll
    for (int kh = 0; kh < 3; ++kh)
      acc = fmaf(cw[(o * 4 + i) * 3 + kh], xi[kh * 64], acc);
  }
  t[idx] = fmaxf(acc, 0.f);
}

// ---------------- big gram (init HOSVD): G = X X^T over fibers ----------------
#define GRAM_BLOCKS 240
template<int D, long long QQ, bool TRANS>
__global__ void kgram_big(const float* __restrict__ T, float* __restrict__ part,
                          int P) {
  constexpr int C = 64;
  constexpr int SUB = (D + 63) / 64;
  constexpr int DP = SUB * 64;
  __shared__ float tile[DP * (C + 1)];
  const int tid = threadIdx.x;                 // 256
  const int ta = tid >> 4, tb = tid & 15;
  float acc[SUB][SUB][4][4];
#pragma unroll
  for (int a = 0; a < SUB; ++a)
#pragma unroll
    for (int b = 0; b < SUB; ++b)
#pragma unroll
      for (int i = 0; i < 4; ++i)
#pragma unroll
        for (int j = 0; j < 4; ++j) acc[a][b][i][j] = 0.f;

  const long long nfib = (long long)P * QQ;
  const int nchunk = (int)(nfib / C);
  for (int ch = blockIdx.x; ch < nchunk; ch += gridDim.x) {
    const long long base = (long long)ch * C;
    __syncthreads();
    if (TRANS) {
      for (int e = tid; e < D * C; e += 256) {
        int a = e & 63, cc = e >> 6;
        tile[a * (C + 1) + cc] = T[base * D + e];
      }
    } else {
      for (int e = tid; e < DP * C; e += 256) {
        int a = e / C, cc = e % C;
        float v = 0.f;
        if (a < D) {
          long long f = base + cc;
          long long p = f / QQ, q = f - p * QQ;   // compile-time QQ
          v = T[(p * D + a) * QQ + q];
        }
        tile[a * (C + 1) + cc] = v;
      }
    }
    __syncthreads();
    for (int cc = 0; cc < C; ++cc) {
      float av[SUB][4], bv[SUB][4];
#pragma unroll
      for (int si = 0; si < SUB; ++si)
#pragma unroll
        for (int i = 0; i < 4; ++i) av[si][i] = tile[(si * 64 + ta * 4 + i) * (C + 1) + cc];
#pragma unroll
      for (int sj = 0; sj < SUB; ++sj)
#pragma unroll
        for (int j = 0; j < 4; ++j) bv[sj][j] = tile[(sj * 64 + tb * 4 + j) * (C + 1) + cc];
#pragma unroll
      for (int si = 0; si < SUB; ++si)
#pragma unroll
        for (int sj = 0; sj < SUB; ++sj)
#pragma unroll
          for (int i = 0; i < 4; ++i)
#pragma unroll
            for (int j = 0; j < 4; ++j)
              acc[si][sj][i][j] = fmaf(av[si][i], bv[sj][j], acc[si][sj][i][j]);
    }
  }
  float* pb = part + (long long)blockIdx.x * D * D;
  for (int si = 0; si < SUB; ++si)
    for (int i = 0; i < 4; ++i) {
      int a = si * 64 + ta * 4 + i;
      if (a >= D) continue;
      for (int sj = 0; sj < SUB; ++sj)
        for (int j = 0; j < 4; ++j) {
          int b = sj * 64 + tb * 4 + j;
          if (b >= D) continue;
          pb[a * D + b] = acc[si][sj][i][j];
        }
    }
}

__global__ void kreduce(const float* __restrict__ part, float* __restrict__ G, int DD) {
  int i = blockIdx.x * blockDim.x + threadIdx.x;
  if (i >= DD) return;
  float s = 0.f;
  for (int b = 0; b < GRAM_BLOCKS; ++b) s += part[(long long)b * DD + i];
  G[i] = s;
}

// ---------------- small gram (projected Y) ----------------
__global__ void kgram_small(const float* __restrict__ Y, float* __restrict__ G,
                            int P, int d, int Q) {
  int pair = blockIdx.x * blockDim.x + threadIdx.x;
  if (pair >= d * d) return;
  int a = pair / d, b = pair % d;
  float s = 0.f;
  for (int p = 0; p < P; ++p) {
    const float* ya = Y + ((long long)p * d + a) * Q;
    const float* yb = Y + ((long long)p * d + b) * Q;
    for (int q = 0; q < Q; ++q) s = fmaf(ya[q], yb[q], s);
  }
  G[pair] = s;
}

// ---------------- mode contraction: out[p,j,q] = sum_a F[a,j] in[p,a,q] ----------------
template<int R, long long QV>
__global__ void kcontract(const float* __restrict__ in, const float* __restrict__ F,
                          float* __restrict__ out, int P, int d) {
  long long total = (long long)P * QV;
  long long idx = (long long)blockIdx.x * blockDim.x + threadIdx.x;
  if (idx >= total) return;
  long long p = idx / QV, q = idx - p * QV;
  float acc[R];
#pragma unroll
  for (int j = 0; j < R; ++j) acc[j] = 0.f;
  const float* ip = in + (p * d) * QV + q;
  for (int a = 0; a < d; ++a) {
    float v = ip[(long long)a * QV];
#pragma unroll
    for (int j = 0; j < R; ++j) acc[j] = fmaf(F[a * R + j], v, acc[j]);
  }
  float* op = out + (p * R) * QV + q;
#pragma unroll
  for (int j = 0; j < R; ++j) op[(long long)j * QV] = acc[j];
}

// ---------------- eigh: top-r eigenvectors of symmetric G (n<=128) ----------------
#define EIG_THREADS 1024
#define EIG_WAVES 16

struct __align__(16) ESm {
  float ApkL[8256];              // packed-lower Householder columns (export)
  float colbuf[128];             // current pivot column (16B-aligned)
  float wwf[128];                // w_pre vector
  float slv[8][516];             // invit solver: float4 {u0,u1,u2,-} per i
  float dd[128], ee[128], e2s[128], taus[128], scls[128];
  float vt[8][132];
  float lam[8];
  float red[16];                 // per-wave pu partials
  float sca[4];
};

template<int N, int RR>
__device__ void eig_body(ESm& S, const float* __restrict__ G, float* __restrict__ F) {
  constexpr int NP  = (N <= 32) ? 32 : ((N <= 64) ? 64 : 128);
  constexpr int QL  = NP / 8;          // floats per thread segment (4/8/16)
  constexpr int NC4 = QL / 4;          // float4 chunks per segment (1/2/4)
  const int tid  = threadIdx.x;
  const int lane = tid & 63, wv = tid >> 6;
  const int q    = tid & 7;            // 8 adjacent lanes share a row
  const int row  = tid >> 3;           // 0..127
  const bool actR = (row < N);
  const int l0 = q * QL;

  float4* cb4 = (float4*)S.colbuf;
  float4* ww4 = (float4*)S.wwf;

  // ---- load: thread (row,q) owns A[row][l0 .. l0+QL) in VGPRs ----
  float Ar[QL];
#pragma unroll
  for (int j = 0; j < QL; ++j) Ar[j] = 0.f;
  if (actR) {
#pragma unroll
    for (int j = 0; j < QL; ++j) { int l = l0 + j; if (l < N) Ar[j] = G[row * N + l]; }
  }
  if (row == 0) {                      // colbuf <- column 0 = row 0 (pads exact 0)
#pragma unroll
    for (int c = 0; c < NC4; ++c)
      cb4[(l0 >> 2) + c] = make_float4(Ar[4*c], Ar[4*c+1], Ar[4*c+2], Ar[4*c+3]);
  }
  __syncthreads();

  // ---- Householder tridiagonalization (LAPACK slarfg conventions) ----
  const int wrow0 = wv << 3;           // 8 rows per wave
  for (int i = 0; i <= N - 3; ++i) {
    const bool wact = (wrow0 + 7 >= i + 1) && (wrow0 <= N - 1);
    float tau_i = 0.f, u_row = 0.f, w_pre = 0.f;
    float ul[QL];
    if (wact) {
      float cbs[QL];
#pragma unroll
      for (int c = 0; c < NC4; ++c) {
        float4 t = cb4[(l0 >> 2) + c];
        cbs[4*c] = t.x; cbs[4*c+1] = t.y; cbs[4*c+2] = t.z; cbs[4*c+3] = t.w;
      }
      float alpha = S.colbuf[i + 1];
      float myc   = S.colbuf[row];

      // xnorm2: segment partial + oct reduce (identical across the 8 lanes)
      float nrm = 0.f;
#pragma unroll
      for (int j = 0; j < QL; ++j) {
        int l = l0 + j;
        float v = (l >= i + 2) ? cbs[j] : 0.f;
        nrm = fmaf(v, v, nrm);
      }
      float xnorm2 = oct_sum(nrm);
      float beta, scl_i;
      if (xnorm2 == 0.f) { beta = alpha; tau_i = 0.f; scl_i = 0.f; }
      else {
        float an = sqrtf(alpha * alpha + xnorm2);
        beta = (alpha >= 0.f) ? -an : an;
        tau_i = (beta - alpha) * rcp_(beta);
        scl_i = rcp_(alpha - beta);
      }
#pragma unroll
      for (int j = 0; j < QL; ++j) {
        int l = l0 + j;
        ul[j] = (l == i + 1) ? 1.f : ((l >= i + 2) ? cbs[j] * scl_i : 0.f);
      }
      if (actR) {
        if (row == i + 1) u_row = 1.f;
        else if (row >= i + 2) u_row = myc * scl_i;
      }
      // symv partial + oct reduce
      float s = 0.f;
#pragma unroll
      for (int j = 0; j < QL; ++j) s = fmaf(Ar[j], ul[j], s);
      s = oct_sum(s);
      w_pre = (actR && row >= i + 1) ? tau_i * s : 0.f;
      if (q == 0) S.wwf[row] = w_pre;
      // pu partial: one per wave
      float p2 = (q == 0) ? w_pre * u_row : 0.f;
      p2 = wave_sum64(p2);
      if (lane == 0) S.red[wv] = p2;
      if (row == i + 1 && q == 0) { S.ee[i] = beta; S.taus[i] = tau_i; S.scls[i] = scl_i; }
    } else {
      if (q == 0) S.wwf[row] = 0.f;
      if (lane == 0) S.red[wv] = 0.f;
    }
    __syncthreads();                                   // A: wwf + red visible
    if (wact) {
      float4* r4 = (float4*)S.red;
      float pu = 0.f;
#pragma unroll
      for (int c = 0; c < 4; ++c) { float4 t = r4[c]; pu += ((t.x + t.y) + (t.z + t.w)); }
      float halfc = -0.5f * tau_i * pu;
      float w_row = fmaf(halfc, u_row, w_pre);
      float nu = -u_row, nw = -w_row;
#pragma unroll
      for (int c = 0; c < NC4; ++c) {
        float4 t = ww4[(l0 >> 2) + c];
        float wlq[4] = {t.x, t.y, t.z, t.w};
#pragma unroll
        for (int jj = 0; jj < 4; ++jj) {
          int j = 4 * c + jj;
          float w_l = fmaf(halfc, ul[j], wlq[jj]);
          Ar[j] = fmaf(nu, w_l, fmaf(nw, ul[j], Ar[j]));
        }
      }
      if (row == i + 1) {                              // next pivot column = my row
#pragma unroll
        for (int c = 0; c < NC4; ++c)
          cb4[(l0 >> 2) + c] = make_float4(Ar[4*c], Ar[4*c+1], Ar[4*c+2], Ar[4*c+3]);
      }
    }
    __syncthreads();                                   // B: colbuf visible
  }

  // ---- export diag + packed-lower Householder columns + last off-diag ----
  if (actR) {
    int base = (row * (row - 1)) >> 1;
#pragma unroll
    for (int j = 0; j < QL; ++j) {
      int l = l0 + j;
      if (l == row) S.dd[row] = Ar[j];
      if (l < row)  S.ApkL[base + l] = Ar[j];
      if (row == N - 1 && l == N - 2) S.ee[N - 2] = Ar[j];
    }
  }
  __syncthreads();
  if (tid < N) S.e2s[tid] = (tid >= 1) ? S.ee[tid - 1] * S.ee[tid - 1] : 0.f;

  // ---- Gershgorin bounds + pivmin ----
  if (tid == 0) {
    float lo = 3.4e38f, hi = -3.4e38f, me2 = 0.f;
    for (int ii = 0; ii < N; ++ii) {
      float rad = 0.f;
      if (ii > 0) rad += fabsf(S.ee[ii - 1]);
      if (ii < N - 1) { rad += fabsf(S.ee[ii]); me2 = fmaxf(me2, S.ee[ii] * S.ee[ii]); }
      lo = fminf(lo, S.dd[ii] - rad);
      hi = fmaxf(hi, S.dd[ii] + rad);
    }
    float span = hi - lo;
    S.sca[0] = lo - 0.001f * span - 1e-20f;
    S.sca[1] = hi + 0.001f * span + 1e-20f;
    S.sca[2] = 1.1754944e-38f * fmaxf(1.f, me2);
  }
  __syncthreads();
  const float pivmin = S.sca[2];

  // ---- 33-way multisection: 32 threads per eigenvalue, 6 rounds ----
  {
    const int grp = tid >> 5, gt = tid & 31;
    if (grp < RR) {
      const int krank = N - 1 - grp;
      float lo = S.sca[0], hi = S.sca[1];
      for (int round = 0; round < 6; ++round) {
        float w = (hi - lo) * (1.f / 33.f);
        float sg = fmaf(w, (float)(gt + 1), lo);
        int cnt = 0;
        float qq = S.dd[0] - sg;
        if (qq < 0.f) cnt++;
#pragma unroll 4
        for (int ii = 1; ii < N; ++ii) {
          if (fabsf(qq) < pivmin) qq = -pivmin;
          qq = S.dd[ii] - sg - S.e2s[ii] * rcp_(qq);
          if (qq < 0.f) cnt++;
        }
        float nlo = (cnt <= krank) ? sg : lo;
        float nhi = (cnt >  krank) ? sg : hi;
        nlo = fmaxf(nlo, dppmovf<0xB1>(nlo));  nhi = fminf(nhi, dppmovf<0xB1>(nhi));
        nlo = fmaxf(nlo, dppmovf<0x4E>(nlo));  nhi = fminf(nhi, dppmovf<0x4E>(nhi));
        nlo = fmaxf(nlo, dppmovf<0x124>(nlo)); nhi = fminf(nhi, dppmovf<0x124>(nhi));
        nlo = fmaxf(nlo, dppmovf<0x128>(nlo)); nhi = fminf(nhi, dppmovf<0x128>(nhi));
        nlo = fmaxf(nlo, __shfl_xor(nlo, 16, 32));
        nhi = fminf(nhi, __shfl_xor(nhi, 16, 32));
        lo = fminf(nlo, nhi); hi = fmaxf(nlo, nhi);
      }
      if (gt == 0) S.lam[grp] = 0.5f * (lo + hi) * (1.f + (float)grp * 3e-7f);
    }
  }
  __syncthreads();

  // ---- inverse iteration: float4-packed solver, select pivoting ----
  if (tid < RR) {
    const int j = tid;
    float4* u4 = (float4*)&S.slv[j][0];
    float* vv = &S.vt[j][0];
    const float lj = S.lam[j];
    for (int k = 0; k < N; ++k) vv[k] = 1.f;
    float sc = 1.f;
    for (int itr = 0; itr < 3; ++itr) {
      float d = S.dd[0] - lj;
      float e = S.ee[0];
      float cv = vv[0] * sc;
#pragma unroll 4
      for (int i = 0; i < N - 1; ++i) {
        float bi = S.ee[i];
        float d1 = S.dd[i + 1] - lj;
        float e1 = (i + 1 < N - 1) ? S.ee[i + 1] : 0.f;
        float vnext = vv[i + 1] * sc;
        bool piv = (fabsf(d) >= fabsf(bi));
        float ad = d;
        if (piv && fabsf(ad) < pivmin) ad = (ad >= 0.f ? pivmin : -pivmin);
        float m   = piv ? (bi * rcp_(ad)) : (ad * rcp_(bi));
        float nu0 = piv ? ad : bi;
        float nu1 = piv ? e  : d1;
        float nu2 = piv ? 0.f : e1;
        u4[i] = make_float4(nu0, nu1, nu2, 0.f);
        float nd = piv ? (d1 - m * e) : (e - m * d1);
        float ne = piv ? e1 : (-m * e1);
        vv[i] = piv ? cv : vnext;
        cv = piv ? (vnext - m * cv) : (cv - m * vnext);
        d = nd; e = ne;
      }
      if (fabsf(d) < pivmin) d = (d >= 0.f ? pivmin : -pivmin);
      float vi2 = cv * rcp_(d);
      vv[N - 1] = vi2;
      float mx = fabsf(vi2);
      float4 uN2 = u4[N - 2];
      float vi1 = (vv[N - 2] - uN2.y * vi2) * rcp_(uN2.x);
      vv[N - 2] = vi1;
      mx = fmaxf(mx, fabsf(vi1));
#pragma unroll 4
      for (int i = N - 3; i >= 0; --i) {
        float4 u = u4[i];
        float t = (vv[i] - u.y * vi1 - u.z * vi2) * rcp_(u.x);
        vv[i] = t;
        mx = fmaxf(mx, fabsf(t));
        vi2 = vi1; vi1 = t;
      }
      sc = rcp_(fmaxf(mx, 1e-30f));
    }
    for (int k = 0; k < N; ++k) vv[k] *= sc;   // final normalize (overflow guard)
  }
  __syncthreads();

  // ---- MGS orthonormalization: single wave, DPP reductions ----
  if (wv == 0) {
    const int k1 = lane, k2 = lane + 64;
    for (int j = 0; j < RR; ++j) {
      float vj1 = (k1 < N) ? S.vt[j][k1] : 0.f;
      float vj2 = (k2 < N) ? S.vt[j][k2] : 0.f;
      for (int i2 = 0; i2 < j; ++i2) {
        float a1 = (k1 < N) ? S.vt[i2][k1] : 0.f;
        float a2 = (k2 < N) ? S.vt[i2][k2] : 0.f;
        float p = wave_sum64(vj1 * a1 + vj2 * a2);
        vj1 -= p * a1; vj2 -= p * a2;
      }
      float nn2 = wave_sum64(vj1 * vj1 + vj2 * vj2);
      float inv = rsqrtf(fmaxf(nn2, 1e-33f));
      vj1 *= inv; vj2 *= inv;
      if (k1 < N) S.vt[j][k1] = vj1;
      if (k2 < N) S.vt[j][k2] = vj2;
    }
  }
  __syncthreads();

  // ---- back-transform: v carried in registers; DPP reductions ----
  for (int vec = wv; vec < RR; vec += EIG_WAVES) {
    float* v = &S.vt[vec][0];
    const int k1 = lane, k2 = lane + 64;
    float v1 = (k1 < N) ? v[k1] : 0.f;
    float v2 = (k2 < N) ? v[k2] : 0.f;
    for (int h = N - 3; h >= 0; --h) {
      const float sh = S.scls[h];
      float uk1 = 0.f, uk2 = 0.f;
      if (k1 > h && k1 < N)
        uk1 = (k1 == h + 1) ? 1.f : S.ApkL[((k1 * (k1 - 1)) >> 1) + h] * sh;
      if (k2 > h && k2 < N)
        uk2 = (k2 == h + 1) ? 1.f : S.ApkL[((k2 * (k2 - 1)) >> 1) + h] * sh;
      float dp = wave_sum64(uk1 * v1 + uk2 * v2);
      float c = S.taus[h] * dp;
      v1 -= c * uk1; v2 -= c * uk2;
    }
    if (k1 < N) v[k1] = v1;
    if (k2 < N) v[k2] = v2;
  }
  __syncthreads();

  // ---- canonical sign (max-|component| positive) + write F (N x RR) ----
  for (int vec = wv; vec < RR; vec += EIG_WAVES) {
    float* v = &S.vt[vec][0];
    float ma = -1.f; int mi = 0x7fffffff;
    for (int k = lane; k < N; k += 64) {
      float a = fabsf(v[k]);
      if (a > ma || (a == ma && k < mi)) { ma = a; mi = k; }
    }
#pragma unroll
    for (int off = 32; off > 0; off >>= 1) {
      float oa = __shfl_down(ma, off, 64);
      int oi = __shfl_down(mi, off, 64);
      if (oa > ma || (oa == ma && oi < mi)) { ma = oa; mi = oi; }
    }
    mi = __shfl(mi, 0, 64);
    float sg = (v[mi] < 0.f) ? -1.f : 1.f;
    for (int k = lane; k < N; k += 64) F[k * RR + vec] = sg * v[k];
  }
}

__global__ __launch_bounds__(EIG_THREADS, 1)
void keigh_init(const float* G0, float* F0, const float* G1, float* F1,
                const float* G2, float* F2, const float* G3, float* F3) {
  __shared__ ESm S;
  if (blockIdx.x == 0)      eig_body<32, 8>(S, G0, F0);
  else if (blockIdx.x == 1) eig_body<100, 6>(S, G1, F1);
  else if (blockIdx.x == 2) eig_body<128, 6>(S, G2, F2);
  else                      eig_body<64, 6>(S, G3, F3);
}

template<int N, int RR>
__global__ __launch_bounds__(EIG_THREADS, 1)
void keigh_one(const float* __restrict__ G, float* __restrict__ F) {
  __shared__ ESm S;
  eig_body<N, RR>(S, G, F);
}

// ---------------------------------------------------------------------------
extern "C" void kernel_launch(void* const* d_in, const int* in_sizes, int n_in,
                              void* d_out, int out_size, void* d_ws, size_t ws_size,
                              hipStream_t stream) {
  (void)in_sizes; (void)n_in; (void)out_size; (void)ws_size;
  const float* x  = (const float*)d_in[0];
  const float* cw = (const float*)d_in[1];
  const float* cb = (const float*)d_in[2];
  float* out = (float*)d_out;
  float* ws  = (float*)d_ws;

  float* T    = ws + OFF_T;
  float* TC   = ws + OFF_TC;
  float* TB   = ws + OFF_TB;
  float* PART = ws + OFF_PART;
  float* TD0a = ws + OFF_TD0a;
  float* TD0b = ws + OFF_TD0b;
  float* TD   = ws + OFF_TD;
  float* G0   = ws + OFF_G0;
  float* G1   = ws + OFF_G1;
  float* G2   = ws + OFF_G2;
  float* G3   = ws + OFF_G3;
  float* F0   = ws + OFF_F0;
  float* F1   = ws + OFF_F1;
  float* F2   = ws + OFF_F2;
  float* F3   = ws + OFF_F3;

  kconv<<<(26214400 + 255) / 256, 256, 0, stream>>>(x, cw, cb, T);

  // ---- HOSVD init: 4 grams, then one batched 4-block eigh ----
  kgram_big<32, 819200, false><<<GRAM_BLOCKS, 256, 0, stream>>>(T, PART, 1);
  kreduce<<<4, 256, 0, stream>>>(PART, G0, 1024);
  kgram_big<100, 8192, false><<<GRAM_BLOCKS, 256, 0, stream>>>(T, PART, 32);
  kreduce<<<40, 256, 0, stream>>>(PART, G1, 10000);
  kgram_big<128, 64, false><<<GRAM_BLOCKS, 256, 0, stream>>>(T, PART, 3200);
  kreduce<<<64, 256, 0, stream>>>(PART, G2, 16384);
  kgram_big<64, 1, true><<<GRAM_BLOCKS, 256, 0, stream>>>(T, PART, 409600);
  kreduce<<<16, 256, 0, stream>>>(PART, G3, 4096);

  keigh_init<<<4, EIG_THREADS, 0, stream>>>(G0, F0, G1, F1, G2, F2, G3, F3);

  // ---- HOOI sweeps ----
  for (int sweep = 0; sweep < 5; ++sweep) {
    // mode 0: Y = T x1 F1 x2 F2 x3 F3 -> (32,6,6,6)
    kcontract<6, 8192><<<1024, 256, 0, stream>>>(T, F1, TB, 32, 100);
    kcontract<6, 64><<<48, 256, 0, stream>>>(TB, F2, TD0a, 192, 128);
    kcontract<6, 1><<<5, 256, 0, stream>>>(TD0a, F3, TD0b, 1152, 64);
    kgram_small<<<4, 256, 0, stream>>>(TD0b, G0, 1, 32, 216);
    keigh_one<32, 8><<<1, EIG_THREADS, 0, stream>>>(G0, F0);
    // TC = T x0 F0 (reused by modes 1,2,3 and the final core)
    kcontract<8, 819200><<<3200, 256, 0, stream>>>(T, F0, TC, 1, 32);
    // mode 1
    kcontract<6, 64><<<200, 256, 0, stream>>>(TC, F2, TB, 800, 128);
    kcontract<6, 1><<<19, 256, 0, stream>>>(TB, F3, TD, 4800, 64);
    kgram_small<<<40, 256, 0, stream>>>(TD, G0, 8, 100, 36);
    keigh_one<100, 6><<<1, EIG_THREADS, 0, stream>>>(G0, F1);
    // mode 2 (TB = TC x1 F1 also reused by mode 3)
    kcontract<6, 8192><<<256, 256, 0, stream>>>(TC, F1, TB, 8, 100);
    kcontract<6, 1><<<24, 256, 0, stream>>>(TB, F3, TD, 6144, 64);
    kgram_small<<<64, 256, 0, stream>>>(TD, G0, 48, 128, 6);
    keigh_one<128, 6><<<1, EIG_THREADS, 0, stream>>>(G0, F2);
    // mode 3 (reuses TB from mode 2)
    kcontract<6, 64><<<12, 256, 0, stream>>>(TB, F2, TD, 48, 128);
    kgram_small<<<16, 256, 0, stream>>>(TD, G0, 288, 64, 1);
    keigh_one<64, 6><<<1, EIG_THREADS, 0, stream>>>(G0, F3);
  }

  // ---- core = (TC) x1 F1 x2 F2 x3 F3 -> (8,6,6,6) ----
  kcontract<6, 8192><<<256, 256, 0, stream>>>(TC, F1, TB, 8, 100);
  kcontract<6, 64><<<12, 256, 0, stream>>>(TB, F2, TD, 48, 128);
  kcontract<6, 1><<<2, 256, 0, stream>>>(TD, F3, out, 288, 64);
}